// Round 1
// baseline (308.420 us; speedup 1.0000x reference)
//
#include <hip/hip_runtime.h>

#define BATCH 65536
#define NSPL  64
#define CDIM  64
#define TDIM  68          // CDIM + DEGREE + 1
#define SPB   32          // splines per block
#define ROWS  16          // batch rows per block
#define BLOCK (SPB * ROWS) // 512 threads

// Cox-de Boor, degree 3, unsorted knots (no local support -> full recursion).
// Strategy:
//  - Per block: stage t (transposed) in LDS, precompute safe-reciprocal tables
//    D_k[i] = (t[i+k]-t[i]==0) ? 0 : 1/(t[i+k]-t[i]) packed as float4
//    {t_i, D1_i, D2_i, D3_i} -> one ds_read_b128 per systolic step.
//  - Systolic fused recursion: one unrolled 68-step loop computes
//    N0[i-1], N1[i-2], N2[i-3], N3[i-4] and accumulates c[i-4]*N3 per step.
//    Short live ranges keep VGPR pressure low despite "arrays".
//  - Right-denominator(k,i) == Left-denominator(k,i+1), so one table/level.
__global__ __launch_bounds__(BLOCK) void bspline_kernel(
    const float* __restrict__ X,   // [BATCH, NSPL]
    const float* __restrict__ T,   // [NSPL, TDIM]
    const float* __restrict__ C,   // [NSPL, CDIM]
    float* __restrict__ O)         // [BATCH, NSPL]
{
    __shared__ float  ltr[TDIM * SPB];   // raw t transposed: [i][sp]
    __shared__ float4 lt4[TDIM * SPB];   // packed {t, D1, D2, D3}: [i][sp]
    __shared__ float  lc [CDIM * SPB];   // c transposed: [i][sp]

    const int tid = threadIdx.x;
    const int s0  = blockIdx.y * SPB;    // first spline of this block

    // Stage t: coalesced global read (contiguous 32*68 floats), transpose into LDS.
    for (int e = tid; e < TDIM * SPB; e += BLOCK) {
        int sp = e / TDIM;
        int i  = e - sp * TDIM;
        ltr[i * SPB + sp] = T[s0 * TDIM + e];
    }
    // Stage c: coalesced, transposed.
    for (int e = tid; e < CDIM * SPB; e += BLOCK) {
        int sp = e >> 6;       // e / CDIM
        int i  = e & 63;       // e % CDIM
        lc[i * SPB + sp] = C[s0 * CDIM + e];
    }
    __syncthreads();

    // Build packed {t, 1/(t[i+1]-t[i]), 1/(t[i+2]-t[i]), 1/(t[i+3]-t[i])} with 0/0:=0.
    for (int e = tid; e < TDIM * SPB; e += BLOCK) {
        int i  = e >> 5;       // e / SPB
        int sp = e & 31;       // e % SPB
        float ti = ltr[i * SPB + sp];
        float d1 = (i + 1 < TDIM) ? (ltr[(i + 1) * SPB + sp] - ti) : 0.f;
        float d2 = (i + 2 < TDIM) ? (ltr[(i + 2) * SPB + sp] - ti) : 0.f;
        float d3 = (i + 3 < TDIM) ? (ltr[(i + 3) * SPB + sp] - ti) : 0.f;
        float4 v;
        v.x = ti;
        v.y = (d1 == 0.f) ? 0.f : 1.f / d1;
        v.z = (d2 == 0.f) ? 0.f : 1.f / d2;
        v.w = (d3 == 0.f) ? 0.f : 1.f / d3;
        lt4[e] = v;
    }
    __syncthreads();

    const int sp  = tid & (SPB - 1);
    const int r   = tid >> 5;
    const int row = blockIdx.x * ROWS + r;
    const int g   = row * NSPL + s0 + sp;
    const float x = X[g];

    // Systolic Cox-de Boor. All indices compile-time after full unroll.
    float tt[TDIM], D1[TDIM], D2[TDIM], D3[TDIM];
    float N0[TDIM], N1[TDIM], N2[TDIM];
    float acc = 0.f;

    #pragma unroll
    for (int i = 0; i < TDIM; ++i) {
        float4 f = lt4[i * SPB + sp];
        tt[i] = f.x; D1[i] = f.y; D2[i] = f.z; D3[i] = f.w;

        if (i >= 1) {
            // degree-0 indicator: t[i-1] <= x < t[i]
            N0[i - 1] = (tt[i - 1] <= x && x < tt[i]) ? 1.f : 0.f;
        }
        if (i >= 2) {
            int j = i - 2;  // level 1: right num = t[j+2]-x = tt[i]-x
            N1[j] = (x - tt[j]) * D1[j] * N0[j]
                  + (tt[i] - x) * D1[j + 1] * N0[j + 1];
        }
        if (i >= 3) {
            int j = i - 3;  // level 2
            N2[j] = (x - tt[j]) * D2[j] * N1[j]
                  + (tt[i] - x) * D2[j + 1] * N1[j + 1];
        }
        if (i >= 4) {
            int j = i - 4;  // level 3 + dot with coefficients (j covers 0..63)
            float n3 = (x - tt[j]) * D3[j] * N2[j]
                     + (tt[i] - x) * D3[j + 1] * N2[j + 1];
            acc = fmaf(lc[j * SPB + sp], n3, acc);
        }
    }

    O[g] = acc;
}

extern "C" void kernel_launch(void* const* d_in, const int* in_sizes, int n_in,
                              void* d_out, int out_size, void* d_ws, size_t ws_size,
                              hipStream_t stream) {
    const float* X = (const float*)d_in[0];  // [65536, 64]
    const float* T = (const float*)d_in[1];  // [64, 68]
    const float* C = (const float*)d_in[2];  // [64, 64]
    float* O = (float*)d_out;                // [65536, 64]

    dim3 grid(BATCH / ROWS, NSPL / SPB);     // (4096, 2)
    bspline_kernel<<<grid, BLOCK, 0, stream>>>(X, T, C, O);
}

// Round 2
// 166.506 us; speedup vs baseline: 1.8523x; 1.8523x over previous
//
#include <hip/hip_runtime.h>

#define BATCH 65536
#define NSPL  64
#define CDIM  64
#define TDIM  68          // CDIM + DEGREE + 1
#define QI    67          // number of degree-0 intervals (TDIM-1)

// ============================================================================
// Algebraic restructure: S(x) = sum_i N0_i(x) * Q_i(x), where N0_i is the
// degree-0 indicator [t_i <= x < t_{i+1}] and Q_i is a CUBIC in x whose
// coefficients depend only on knots+coeffs (sum over the <=8 Cox-de Boor
// lattice paths from each N3_j, j in [i-3,i], weighted by c_j).
// Prep kernel expands Q in double precision (68.6 KB -> d_ws). Main kernel:
// per element only 67 * (1 rolling cmp + 3 Horner fma + select + add) VALU ops,
// ZERO LDS (round-1 was LDS-pipe-bound: 1 LDS pipe/CU shared by 4 SIMDs, plus
// 3.2e7 bank-conflict cycles in the staging transposes).
// Tables are wave-uniform (one spline per wave per iteration, readfirstlane)
// -> scalar s_load on the idle SMEM pipe.
// ============================================================================

__global__ __launch_bounds__(256) void build_q(const float* __restrict__ T,
                                               const float* __restrict__ C,
                                               float* __restrict__ Q) {
    int gid = blockIdx.x * blockDim.x + threadIdx.x;
    if (gid >= NSPL * QI) return;
    int s = gid / QI;
    int i = gid - s * QI;
    const float* t = T + s * TDIM;
    const float* c = C + s * CDIM;
    double q0 = 0, q1 = 0, q2 = 0, q3 = 0;
    // Linear factors (p*x + r); safe-div: exact-zero denominator -> 0 factor,
    // matching the reference's 0/0 := 0 convention (fp32 diff==0 iff equal).
    for (int j = i - 3; j <= i; ++j) {
        if (j < 0 || j > CDIM - 1) continue;
        double cj = (double)c[j];
        for (int b2 = 0; b2 < 2; ++b2) {
            int m2 = j + b2;
            double p3, r3;
            if (!b2) { double d = (double)t[j+3] - (double)t[j];   double D = (d==0.0)?0.0:1.0/d; p3 =  D; r3 = -D*(double)t[j]; }
            else     { double d = (double)t[j+4] - (double)t[j+1]; double D = (d==0.0)?0.0:1.0/d; p3 = -D; r3 =  D*(double)t[j+4]; }
            for (int b1 = 0; b1 < 2; ++b1) {
                int m1 = m2 + b1;
                double p2, r2;
                if (!b1) { double d = (double)t[m2+2] - (double)t[m2];   double D=(d==0.0)?0.0:1.0/d; p2 =  D; r2 = -D*(double)t[m2]; }
                else     { double d = (double)t[m2+3] - (double)t[m2+1]; double D=(d==0.0)?0.0:1.0/d; p2 = -D; r2 =  D*(double)t[m2+3]; }
                for (int b0 = 0; b0 < 2; ++b0) {
                    if (m1 + b0 != i) continue;   // path must end at interval i
                    double p1, r1;
                    if (!b0) { double d = (double)t[m1+1] - (double)t[m1];   double D=(d==0.0)?0.0:1.0/d; p1 =  D; r1 = -D*(double)t[m1]; }
                    else     { double d = (double)t[m1+2] - (double)t[m1+1]; double D=(d==0.0)?0.0:1.0/d; p1 = -D; r1 =  D*(double)t[m1+2]; }
                    // (p3 x + r3)(p2 x + r2) -> quadratic, then * (p1 x + r1)
                    double a2 = p3*p2, a1 = p3*r2 + r3*p2, a0 = r3*r2;
                    q3 += cj * (a2*p1);
                    q2 += cj * (a2*r1 + a1*p1);
                    q1 += cj * (a1*r1 + a0*p1);
                    q0 += cj * (a0*r1);
                }
            }
        }
    }
    float4 v; v.x = (float)q0; v.y = (float)q1; v.z = (float)q2; v.w = (float)q3;
    ((float4*)Q)[gid] = v;
}

// Block = 256 threads = 4 waves, 64 batch rows. Wave w sweeps splines
// s = 16w..16w+15; spline index is wave-uniform -> T/Q reads scalarize.
// x/out: per-lane stride-256B but the block consumes its whole 16KB row
// region through L1 across the 16 iterations -> HBM traffic stays ideal.
__global__ __launch_bounds__(256) void bspline_main(const float* __restrict__ X,
                                                    const float* __restrict__ T,
                                                    const float* __restrict__ Q,
                                                    float* __restrict__ O) {
    const int lane = threadIdx.x & 63;
    const int w    = threadIdx.x >> 6;
    const int row  = blockIdx.x * 64 + lane;
    const int base = row * NSPL + w * 16;

    #pragma unroll 1
    for (int k = 0; k < 16; ++k) {
        const int s = __builtin_amdgcn_readfirstlane(w * 16 + k);
        const float*  ts = T + s * TDIM;
        const float4* qs = (const float4*)Q + s * QI;
        const float x = X[base + k];
        float a = 0.f;
        float tn = ts[0];
        bool ge = (x >= tn);                 // rolling: ind_i = ge_i && !ge_{i+1}
        #pragma unroll
        for (int i = 0; i < QI; ++i) {
            float tnn = ts[i + 1];
            bool ge2 = (x >= tnn);
            float4 q = qs[i];
            float p = fmaf(fmaf(fmaf(q.w, x, q.z), x, q.y), x, q.x);
            a += (ge && !ge2) ? p : 0.f;
            ge = ge2;
        }
        O[base + k] = a;
    }
}

// ---------------- round-1 fallback (only if ws too small) ----------------
#define SPB   32
#define ROWS  16
#define BLOCK (SPB * ROWS)
__global__ __launch_bounds__(BLOCK) void bspline_fallback(
    const float* __restrict__ X, const float* __restrict__ T,
    const float* __restrict__ C, float* __restrict__ O)
{
    __shared__ float  ltr[TDIM * SPB];
    __shared__ float4 lt4[TDIM * SPB];
    __shared__ float  lc [CDIM * SPB];
    const int tid = threadIdx.x;
    const int s0  = blockIdx.y * SPB;
    for (int e = tid; e < TDIM * SPB; e += BLOCK) {
        int sp = e / TDIM; int i = e - sp * TDIM;
        ltr[i * SPB + sp] = T[s0 * TDIM + e];
    }
    for (int e = tid; e < CDIM * SPB; e += BLOCK) {
        int sp = e >> 6; int i = e & 63;
        lc[i * SPB + sp] = C[s0 * CDIM + e];
    }
    __syncthreads();
    for (int e = tid; e < TDIM * SPB; e += BLOCK) {
        int i = e >> 5; int sp = e & 31;
        float ti = ltr[i * SPB + sp];
        float d1 = (i + 1 < TDIM) ? (ltr[(i + 1) * SPB + sp] - ti) : 0.f;
        float d2 = (i + 2 < TDIM) ? (ltr[(i + 2) * SPB + sp] - ti) : 0.f;
        float d3 = (i + 3 < TDIM) ? (ltr[(i + 3) * SPB + sp] - ti) : 0.f;
        float4 v; v.x = ti;
        v.y = (d1 == 0.f) ? 0.f : 1.f / d1;
        v.z = (d2 == 0.f) ? 0.f : 1.f / d2;
        v.w = (d3 == 0.f) ? 0.f : 1.f / d3;
        lt4[e] = v;
    }
    __syncthreads();
    const int sp = tid & (SPB - 1);
    const int r  = tid >> 5;
    const int g  = (blockIdx.x * ROWS + r) * NSPL + s0 + sp;
    const float x = X[g];
    float tt[TDIM], D1[TDIM], D2[TDIM], D3[TDIM];
    float N0[TDIM], N1[TDIM], N2[TDIM];
    float acc = 0.f;
    #pragma unroll
    for (int i = 0; i < TDIM; ++i) {
        float4 f = lt4[i * SPB + sp];
        tt[i] = f.x; D1[i] = f.y; D2[i] = f.z; D3[i] = f.w;
        if (i >= 1) N0[i-1] = (tt[i-1] <= x && x < tt[i]) ? 1.f : 0.f;
        if (i >= 2) { int j = i-2; N1[j] = (x-tt[j])*D1[j]*N0[j] + (tt[i]-x)*D1[j+1]*N0[j+1]; }
        if (i >= 3) { int j = i-3; N2[j] = (x-tt[j])*D2[j]*N1[j] + (tt[i]-x)*D2[j+1]*N1[j+1]; }
        if (i >= 4) { int j = i-4; float n3 = (x-tt[j])*D3[j]*N2[j] + (tt[i]-x)*D3[j+1]*N2[j+1];
                      acc = fmaf(lc[j * SPB + sp], n3, acc); }
    }
    O[g] = acc;
}

extern "C" void kernel_launch(void* const* d_in, const int* in_sizes, int n_in,
                              void* d_out, int out_size, void* d_ws, size_t ws_size,
                              hipStream_t stream) {
    const float* X = (const float*)d_in[0];  // [65536, 64]
    const float* T = (const float*)d_in[1];  // [64, 68]
    const float* C = (const float*)d_in[2];  // [64, 64]
    float* O = (float*)d_out;                // [65536, 64]

    const size_t q_bytes = (size_t)NSPL * QI * 4 * sizeof(float);  // 68608 B
    if (ws_size >= q_bytes) {
        float* Q = (float*)d_ws;
        build_q<<<(NSPL * QI + 255) / 256, 256, 0, stream>>>(T, C, Q);
        bspline_main<<<BATCH / 64, 256, 0, stream>>>(X, T, Q, O);
    } else {
        dim3 grid(BATCH / ROWS, NSPL / SPB);
        bspline_fallback<<<grid, BLOCK, 0, stream>>>(X, T, C, O);
    }
}

// Round 3
// 165.011 us; speedup vs baseline: 1.8691x; 1.0091x over previous
//
#include <hip/hip_runtime.h>

#define BATCH 65536
#define NSPL  64
#define CDIM  64
#define TDIM  68          // CDIM + DEGREE + 1
#define QI    67          // number of degree-0 intervals (TDIM-1)
#define PITCH 65          // LDS row pitch (64+1) -> bank-stride 1 on transposed access

// ============================================================================
// S(x) = sum_i [t_i <= x < t_{i+1}] * Q_i(x), Q_i cubic in x precomputed from
// knots+coeffs (<=8 Cox-de Boor lattice paths per Q_i, fp64 prep -> d_ws).
//
// Round-2 lesson (counters): compute mapping (wave-uniform spline -> scalar
// s_load tables, VALU-only inner loop) is right, but per-lane stride-256B
// global I/O caused 16x HBM write amplification (WRITE_SIZE 255MB vs 16.8MB
// ideal: every dword store -> one 64B partial-line writeback).
// Round-3 fix: 64rows x 64splines block tile, coalesced global I/O, LDS
// transpose both ways with pitch-65 (all four access phases bank-conflict
// free: stride-65 <-> bank-stride-1, stride-1 <-> 2 lanes/bank = free).
// ============================================================================

__global__ __launch_bounds__(256) void build_q(const float* __restrict__ T,
                                               const float* __restrict__ C,
                                               float* __restrict__ Q) {
    int gid = blockIdx.x * blockDim.x + threadIdx.x;
    if (gid >= NSPL * QI) return;
    int s = gid / QI;
    int i = gid - s * QI;
    const float* t = T + s * TDIM;
    const float* c = C + s * CDIM;
    double q0 = 0, q1 = 0, q2 = 0, q3 = 0;
    // Linear factors (p*x + r); safe-div: exact-zero fp32 denominator -> 0,
    // matching the reference's 0/0 := 0 convention.
    for (int j = i - 3; j <= i; ++j) {
        if (j < 0 || j > CDIM - 1) continue;
        double cj = (double)c[j];
        for (int b2 = 0; b2 < 2; ++b2) {
            int m2 = j + b2;
            double p3, r3;
            if (!b2) { double d = (double)t[j+3] - (double)t[j];   double D = (d==0.0)?0.0:1.0/d; p3 =  D; r3 = -D*(double)t[j]; }
            else     { double d = (double)t[j+4] - (double)t[j+1]; double D = (d==0.0)?0.0:1.0/d; p3 = -D; r3 =  D*(double)t[j+4]; }
            for (int b1 = 0; b1 < 2; ++b1) {
                int m1 = m2 + b1;
                double p2, r2;
                if (!b1) { double d = (double)t[m2+2] - (double)t[m2];   double D=(d==0.0)?0.0:1.0/d; p2 =  D; r2 = -D*(double)t[m2]; }
                else     { double d = (double)t[m2+3] - (double)t[m2+1]; double D=(d==0.0)?0.0:1.0/d; p2 = -D; r2 =  D*(double)t[m2+3]; }
                for (int b0 = 0; b0 < 2; ++b0) {
                    if (m1 + b0 != i) continue;   // path must end at interval i
                    double p1, r1;
                    if (!b0) { double d = (double)t[m1+1] - (double)t[m1];   double D=(d==0.0)?0.0:1.0/d; p1 =  D; r1 = -D*(double)t[m1]; }
                    else     { double d = (double)t[m1+2] - (double)t[m1+1]; double D=(d==0.0)?0.0:1.0/d; p1 = -D; r1 =  D*(double)t[m1+2]; }
                    double a2 = p3*p2, a1 = p3*r2 + r3*p2, a0 = r3*r2;
                    q3 += cj * (a2*p1);
                    q2 += cj * (a2*r1 + a1*p1);
                    q1 += cj * (a1*r1 + a0*p1);
                    q0 += cj * (a0*r1);
                }
            }
        }
    }
    float4 v; v.x = (float)q0; v.y = (float)q1; v.z = (float)q2; v.w = (float)q3;
    ((float4*)Q)[gid] = v;
}

// Block = 256 threads = 4 waves; tile = 64 batch rows x 64 splines.
// Wave w sweeps splines s = 16w..16w+15 (wave-uniform -> T/Q scalarize to
// s_load on the SMEM pipe). lane = row within tile.
__global__ __launch_bounds__(256) void bspline_main(const float* __restrict__ X,
                                                    const float* __restrict__ T,
                                                    const float* __restrict__ Q,
                                                    float* __restrict__ O) {
    __shared__ float xl[NSPL * PITCH];   // x transposed: [spline][row]
    __shared__ float ol[NSPL * PITCH];   // out transposed: [spline][row]

    const int lane = threadIdx.x & 63;
    const int w    = threadIdx.x >> 6;
    const int row0 = blockIdx.x * 64;

    // Stage X: coalesced global (lane = spline), conflict-free LDS write
    // (addr stride PITCH=65 dwords -> bank stride 1).
    #pragma unroll
    for (int j = 0; j < 16; ++j) {
        int e = threadIdx.x + j * 256;
        int r = e >> 6, s = e & 63;
        xl[s * PITCH + r] = X[(row0 + r) * NSPL + s];
    }
    __syncthreads();

    #pragma unroll 1
    for (int k = 0; k < 16; ++k) {
        const int s = __builtin_amdgcn_readfirstlane(w * 16 + k);
        const float*  ts = T + s * TDIM;
        const float4* qs = (const float4*)Q + s * QI;
        const float x = xl[s * PITCH + lane];      // stride-1: conflict-free
        float a = 0.f;
        bool ge = (x >= ts[0]);                    // rolling comparison chain
        #pragma unroll
        for (int i = 0; i < QI; ++i) {
            bool ge2 = (x >= ts[i + 1]);
            float4 q = qs[i];
            float p = fmaf(fmaf(fmaf(q.w, x, q.z), x, q.y), x, q.x);
            a += (ge && !ge2) ? p : 0.f;
            ge = ge2;
        }
        ol[s * PITCH + lane] = a;                  // stride-1: conflict-free
    }
    __syncthreads();

    // Write-back: transposed LDS read (stride 65 -> bank stride 1, free),
    // coalesced global store (lane = spline, 256B/wave segment).
    #pragma unroll
    for (int j = 0; j < 16; ++j) {
        int e = threadIdx.x + j * 256;
        int r = e >> 6, s = e & 63;
        O[(row0 + r) * NSPL + s] = ol[s * PITCH + r];
    }
}

extern "C" void kernel_launch(void* const* d_in, const int* in_sizes, int n_in,
                              void* d_out, int out_size, void* d_ws, size_t ws_size,
                              hipStream_t stream) {
    const float* X = (const float*)d_in[0];  // [65536, 64]
    const float* T = (const float*)d_in[1];  // [64, 68]
    const float* C = (const float*)d_in[2];  // [64, 64]
    float* O = (float*)d_out;                // [65536, 64]

    float* Q = (float*)d_ws;                 // 64*67*4 floats = 68.6 KB
    build_q<<<(NSPL * QI + 255) / 256, 256, 0, stream>>>(T, C, Q);
    bspline_main<<<BATCH / 64, 256, 0, stream>>>(X, T, Q, O);
}

// Round 4
// 128.531 us; speedup vs baseline: 2.3996x; 1.2838x over previous
//
#include <hip/hip_runtime.h>

#define BATCH 65536
#define NSPL  64
#define CDIM  64
#define TDIM  68          // CDIM + DEGREE + 1
#define QI    67          // number of degree-0 intervals (TDIM-1)

#define RPT    4          // rows per thread per spline
#define TROWS  256        // tile rows = 64 lanes * RPT
#define TCOLS  16         // splines per block (one 64B-line column group)
#define LPITCH 273        // 273 % 32 == 17 (odd): stage 2-way (free), compute stride-1 (free)

// ============================================================================
// S(x) = sum_i [t_i <= x < t_{i+1}] * Q_i(x); Q_i cubic, fp64 prep -> d_ws.
//
// Round-3 lesson: WRITE amplification fixed (255MB->16.4MB) but dur only
// 110->100us. Issue arithmetic: ~470 VALU/elem = ~25us of pure issue vs
// 100us wall -> waves are lgkmcnt-stalled on the scalar Q/t stream (1 table
// fetch per 1 element of work, SGPR budget caps prefetch depth).
// Round-4 fix: interval-OUTER loop with R=4 rows/lane in registers: one
// scalar q-load now feeds 4x6=24 VALU instrs, and unrolling lets the
// compiler run the s_load stream several intervals ahead. Tables stay
// wave-uniform (spline fixed per wave-phase -> s_load on SMEM pipe).
// 16-spline column groups = exactly one aligned 64B line per row for both
// X and O; single in-place LDS tile (column owned by one wave).
// ============================================================================

__global__ __launch_bounds__(256) void build_q(const float* __restrict__ T,
                                               const float* __restrict__ C,
                                               float* __restrict__ Q) {
    int gid = blockIdx.x * blockDim.x + threadIdx.x;
    if (gid >= NSPL * QI) return;
    int s = gid / QI;
    int i = gid - s * QI;
    const float* t = T + s * TDIM;
    const float* c = C + s * CDIM;
    double q0 = 0, q1 = 0, q2 = 0, q3 = 0;
    // Linear factors (p*x + r); safe-div: exact-zero fp32 denominator -> 0,
    // matching the reference's 0/0 := 0 convention.
    for (int j = i - 3; j <= i; ++j) {
        if (j < 0 || j > CDIM - 1) continue;
        double cj = (double)c[j];
        for (int b2 = 0; b2 < 2; ++b2) {
            int m2 = j + b2;
            double p3, r3;
            if (!b2) { double d = (double)t[j+3] - (double)t[j];   double D = (d==0.0)?0.0:1.0/d; p3 =  D; r3 = -D*(double)t[j]; }
            else     { double d = (double)t[j+4] - (double)t[j+1]; double D = (d==0.0)?0.0:1.0/d; p3 = -D; r3 =  D*(double)t[j+4]; }
            for (int b1 = 0; b1 < 2; ++b1) {
                int m1 = m2 + b1;
                double p2, r2;
                if (!b1) { double d = (double)t[m2+2] - (double)t[m2];   double D=(d==0.0)?0.0:1.0/d; p2 =  D; r2 = -D*(double)t[m2]; }
                else     { double d = (double)t[m2+3] - (double)t[m2+1]; double D=(d==0.0)?0.0:1.0/d; p2 = -D; r2 =  D*(double)t[m2+3]; }
                for (int b0 = 0; b0 < 2; ++b0) {
                    if (m1 + b0 != i) continue;   // path must end at interval i
                    double p1, r1;
                    if (!b0) { double d = (double)t[m1+1] - (double)t[m1];   double D=(d==0.0)?0.0:1.0/d; p1 =  D; r1 = -D*(double)t[m1]; }
                    else     { double d = (double)t[m1+2] - (double)t[m1+1]; double D=(d==0.0)?0.0:1.0/d; p1 = -D; r1 =  D*(double)t[m1+2]; }
                    double a2 = p3*p2, a1 = p3*r2 + r3*p2, a0 = r3*r2;
                    q3 += cj * (a2*p1);
                    q2 += cj * (a2*r1 + a1*p1);
                    q1 += cj * (a1*r1 + a0*p1);
                    q0 += cj * (a0*r1);
                }
            }
        }
    }
    float4 v; v.x = (float)q0; v.y = (float)q1; v.z = (float)q2; v.w = (float)q3;
    ((float4*)Q)[gid] = v;
}

__global__ __launch_bounds__(256) void bspline_main(const float* __restrict__ X,
                                                    const float* __restrict__ T,
                                                    const float* __restrict__ Q,
                                                    float* __restrict__ O) {
    __shared__ float xl[TCOLS * LPITCH];   // [col][row]; reused in-place for output

    const int lane = threadIdx.x & 63;
    const int w    = threadIdx.x >> 6;
    const int r0   = blockIdx.x * TROWS;
    const int s0   = blockIdx.y * TCOLS;

    // Stage in: each row contributes one full, aligned 64B line (cols s0..s0+15).
    // LDS write banks (17c + r) % 32: max 2-way within a wave -> free.
    #pragma unroll
    for (int it = 0; it < TROWS * TCOLS / 256; ++it) {    // 16 iters
        int e = threadIdx.x + it * 256;
        int r = e >> 4, c = e & 15;
        xl[c * LPITCH + r] = X[(r0 + r) * NSPL + s0 + c];
    }
    __syncthreads();

    // Each wave owns columns 4w..4w+3; processes them one spline at a time,
    // RPT rows per lane held in registers.
    #pragma unroll 1
    for (int cc = 0; cc < 4; ++cc) {
        const int c = w * 4 + cc;
        const int s = __builtin_amdgcn_readfirstlane(s0 + c);
        const float*  ts = T + s * TDIM;
        const float4* qs = (const float4*)Q + s * QI;

        float xv[RPT], acc[RPT];
        bool  ge[RPT];
        #pragma unroll
        for (int j = 0; j < RPT; ++j) {
            xv[j]  = xl[c * LPITCH + lane + 64 * j];   // stride-1: conflict-free
            acc[j] = 0.f;
        }
        {
            float t0 = ts[0];
            #pragma unroll
            for (int j = 0; j < RPT; ++j) ge[j] = (xv[j] >= t0);
        }
        #pragma unroll
        for (int i = 0; i < QI; ++i) {
            float  tn = ts[i + 1];
            float4 q  = qs[i];
            #pragma unroll
            for (int j = 0; j < RPT; ++j) {
                bool  ge2 = (xv[j] >= tn);
                float p   = fmaf(fmaf(fmaf(q.w, xv[j], q.z), xv[j], q.y), xv[j], q.x);
                acc[j] += (ge[j] && !ge2) ? p : 0.f;
                ge[j]  = ge2;
            }
        }
        // In-place write-back: column c is only touched by this wave, and all
        // lanes read xv before any write (wave-lockstep) -> no barrier needed.
        #pragma unroll
        for (int j = 0; j < RPT; ++j)
            xl[c * LPITCH + lane + 64 * j] = acc[j];
    }
    __syncthreads();

    // Write out: transposed LDS read (2-way max, free), one full 64B line per row.
    #pragma unroll
    for (int it = 0; it < TROWS * TCOLS / 256; ++it) {
        int e = threadIdx.x + it * 256;
        int r = e >> 4, c = e & 15;
        O[(r0 + r) * NSPL + s0 + c] = xl[c * LPITCH + r];
    }
}

extern "C" void kernel_launch(void* const* d_in, const int* in_sizes, int n_in,
                              void* d_out, int out_size, void* d_ws, size_t ws_size,
                              hipStream_t stream) {
    const float* X = (const float*)d_in[0];  // [65536, 64]
    const float* T = (const float*)d_in[1];  // [64, 68]
    const float* C = (const float*)d_in[2];  // [64, 64]
    float* O = (float*)d_out;                // [65536, 64]

    float* Q = (float*)d_ws;                 // 64*67*4 floats = 68.6 KB
    build_q<<<(NSPL * QI + 255) / 256, 256, 0, stream>>>(T, C, Q);
    dim3 grid(BATCH / TROWS, NSPL / TCOLS);  // (256, 4)
    bspline_main<<<grid, 256, 0, stream>>>(X, T, Q, O);
}

// Round 5
// 113.852 us; speedup vs baseline: 2.7089x; 1.1289x over previous
//
#include <hip/hip_runtime.h>

#define BATCH 65536
#define NSPL  64
#define CDIM  64
#define TDIM  68          // CDIM + DEGREE + 1
#define QI    67          // number of degree-0 intervals (TDIM-1)

#define RPT    4          // rows per thread per spline
#define TROWS  256        // tile rows = 64 lanes * RPT
#define TCOLS  8          // splines per block -> grid 2048 = 8 blocks/CU
#define LPITCH 264        // 264 % 32 == 8: all LDS phases <=2-way (free)

typedef float v2f __attribute__((ext_vector_type(2)));

static __device__ __forceinline__ v2f splat2(float f) { v2f v; v.x = f; v.y = f; return v; }
static __device__ __forceinline__ v2f fma2(v2f a, v2f b, v2f c) {
#if __has_builtin(__builtin_elementwise_fma)
    return __builtin_elementwise_fma(a, b, c);
#else
    v2f r; r.x = fmaf(a.x, b.x, c.x); r.y = fmaf(a.y, b.y, c.y); return r;
#endif
}

// ============================================================================
// S(x) = sum_i [t_i <= x < t_{i+1}] * Q_i(x); Q_i cubic, fp64 prep -> d_ws.
// Round-4 lessons: (a) grid 1024 = 4 blocks/CU capped occupancy at 34% ->
// 2048 blocks now; (b) build_q's serialized fp64 divisions cost ~20us of
// bench time -> cooperative one-block-per-spline rewrite, 3 LDS recip tables,
// Q expansion division-free; (c) inner loop packed (v_pk_fma_f32): 16 VALU
// per (interval x 4 rows) vs 24 -> 14.3us VALU floor.
// ============================================================================

__global__ __launch_bounds__(128) void build_q(const float* __restrict__ T,
                                               const float* __restrict__ C,
                                               float* __restrict__ Q) {
    __shared__ double td[TDIM];
    __shared__ double cd[CDIM];
    __shared__ double R1[TDIM - 1], R2[TDIM - 2], R3[TDIM - 3];
    const int s   = blockIdx.x;
    const int tid = threadIdx.x;

    if (tid < TDIM) td[tid] = (double)T[s * TDIM + tid];
    if (tid >= 64 && tid < 64 + CDIM) cd[tid - 64] = (double)C[s * CDIM + tid - 64];
    __syncthreads();
    // Safe reciprocals; fl(a-b)==0 iff a==b for fp32, and exact double diff
    // is 0 iff fp32 diff is 0 -> matches reference's 0/0:=0 on fp32 denoms.
    if (tid < TDIM - 1) { double d = td[tid + 1] - td[tid]; R1[tid] = (d == 0.0) ? 0.0 : 1.0 / d; }
    if (tid < TDIM - 2) { double d = td[tid + 2] - td[tid]; R2[tid] = (d == 0.0) ? 0.0 : 1.0 / d; }
    if (tid < TDIM - 3) { double d = td[tid + 3] - td[tid]; R3[tid] = (d == 0.0) ? 0.0 : 1.0 / d; }
    __syncthreads();

    if (tid >= QI) return;
    const int i = tid;
    double q0 = 0, q1 = 0, q2 = 0, q3 = 0;
    for (int j = i - 3; j <= i; ++j) {
        if (j < 0 || j > CDIM - 1) continue;
        double cj = cd[j];
        for (int b2 = 0; b2 < 2; ++b2) {
            int m2 = j + b2;
            double D3 = b2 ? R3[j + 1] : R3[j];
            double p3 = b2 ? -D3 : D3;
            double r3 = b2 ? D3 * td[j + 4] : -D3 * td[j];
            for (int b1 = 0; b1 < 2; ++b1) {
                int m1 = m2 + b1;
                double D2 = b1 ? R2[m2 + 1] : R2[m2];
                double p2 = b1 ? -D2 : D2;
                double r2 = b1 ? D2 * td[m2 + 3] : -D2 * td[m2];
                for (int b0 = 0; b0 < 2; ++b0) {
                    if (m1 + b0 != i) continue;   // path must end at interval i
                    double D1 = b0 ? R1[m1 + 1] : R1[m1];
                    double p1 = b0 ? -D1 : D1;
                    double r1 = b0 ? D1 * td[m1 + 2] : -D1 * td[m1];
                    double a2 = p3 * p2, a1 = p3 * r2 + r3 * p2, a0 = r3 * r2;
                    q3 += cj * (a2 * p1);
                    q2 += cj * (a2 * r1 + a1 * p1);
                    q1 += cj * (a1 * r1 + a0 * p1);
                    q0 += cj * (a0 * r1);
                }
            }
        }
    }
    float4 v; v.x = (float)q0; v.y = (float)q1; v.z = (float)q2; v.w = (float)q3;
    ((float4*)Q)[s * QI + i] = v;
}

// Block = 256 threads = 4 waves; tile = 256 rows x 8 splines. Wave w owns
// columns 2w, 2w+1 (wave-uniform spline -> scalar s_load tables on SMEM pipe).
__global__ __launch_bounds__(256) void bspline_main(const float* __restrict__ X,
                                                    const float* __restrict__ T,
                                                    const float* __restrict__ Q,
                                                    float* __restrict__ O) {
    __shared__ float xl[TCOLS * LPITCH];   // [col][row]; reused in-place for output

    const int lane = threadIdx.x & 63;
    const int w    = threadIdx.x >> 6;
    const int r0   = blockIdx.x * TROWS;
    const int s0   = blockIdx.y * TCOLS;

    // Stage in: per wave 8 rows x 32B segments; LDS banks (8c + r) % 32 -> 2-way max.
    #pragma unroll
    for (int it = 0; it < TROWS * TCOLS / 256; ++it) {    // 8 iters
        int e = threadIdx.x + it * 256;
        int r = e >> 3, c = e & 7;
        xl[c * LPITCH + r] = X[(r0 + r) * NSPL + s0 + c];
    }
    __syncthreads();

    #pragma unroll
    for (int cc = 0; cc < 2; ++cc) {
        const int c = w * 2 + cc;
        const int s = __builtin_amdgcn_readfirstlane(s0 + c);
        const float*  ts = T + s * TDIM;
        const float4* qs = (const float4*)Q + s * QI;

        v2f x01, x23;
        x01.x = xl[c * LPITCH + lane];
        x01.y = xl[c * LPITCH + lane + 64];
        x23.x = xl[c * LPITCH + lane + 128];
        x23.y = xl[c * LPITCH + lane + 192];
        v2f a01 = splat2(0.f), a23 = splat2(0.f);

        float t0 = ts[0];
        bool ge0 = (x01.x >= t0), ge1 = (x01.y >= t0);
        bool ge2 = (x23.x >= t0), ge3 = (x23.y >= t0);

        #pragma unroll
        for (int i = 0; i < QI; ++i) {
            float  tn = ts[i + 1];
            float4 q  = qs[i];
            v2f qw = splat2(q.w), qz = splat2(q.z), qy = splat2(q.y), qx = splat2(q.x);

            v2f p01 = fma2(qw, x01, qz);
            p01 = fma2(p01, x01, qy);
            p01 = fma2(p01, x01, qx);
            v2f p23 = fma2(qw, x23, qz);
            p23 = fma2(p23, x23, qy);
            p23 = fma2(p23, x23, qx);

            bool g0 = (x01.x >= tn), g1 = (x01.y >= tn);
            bool g2 = (x23.x >= tn), g3 = (x23.y >= tn);
            v2f ind01, ind23;
            ind01.x = (ge0 && !g0) ? 1.f : 0.f;
            ind01.y = (ge1 && !g1) ? 1.f : 0.f;
            ind23.x = (ge2 && !g2) ? 1.f : 0.f;
            ind23.y = (ge3 && !g3) ? 1.f : 0.f;
            a01 = fma2(ind01, p01, a01);
            a23 = fma2(ind23, p23, a23);
            ge0 = g0; ge1 = g1; ge2 = g2; ge3 = g3;
        }

        // In-place write-back: column c touched only by this wave, all xv
        // reads happened before (wave lockstep) -> no barrier needed here.
        xl[c * LPITCH + lane]       = a01.x;
        xl[c * LPITCH + lane + 64]  = a01.y;
        xl[c * LPITCH + lane + 128] = a23.x;
        xl[c * LPITCH + lane + 192] = a23.y;
    }
    __syncthreads();

    // Write out: LDS read 2-way max; global 32B segments, line-pairs merged in
    // L2 (y-partner block is 256 apart in dispatch order = same XCD).
    #pragma unroll
    for (int it = 0; it < TROWS * TCOLS / 256; ++it) {
        int e = threadIdx.x + it * 256;
        int r = e >> 3, c = e & 7;
        O[(r0 + r) * NSPL + s0 + c] = xl[c * LPITCH + r];
    }
}

extern "C" void kernel_launch(void* const* d_in, const int* in_sizes, int n_in,
                              void* d_out, int out_size, void* d_ws, size_t ws_size,
                              hipStream_t stream) {
    const float* X = (const float*)d_in[0];  // [65536, 64]
    const float* T = (const float*)d_in[1];  // [64, 68]
    const float* C = (const float*)d_in[2];  // [64, 64]
    float* O = (float*)d_out;                // [65536, 64]

    float* Q = (float*)d_ws;                 // 64*67*4 floats = 68.6 KB
    build_q<<<NSPL, 128, 0, stream>>>(T, C, Q);
    dim3 grid(BATCH / TROWS, NSPL / TCOLS);  // (256, 8) = 2048 blocks
    bspline_main<<<grid, 256, 0, stream>>>(X, T, Q, O);
}